// Round 4
// baseline (471.169 us; speedup 1.0000x reference)
//
#include <hip/hip_runtime.h>

#define TAU 8e-3f

typedef __attribute__((ext_vector_type(8))) short bf16x8;
typedef __attribute__((ext_vector_type(4))) float f32x4;
typedef __attribute__((ext_vector_type(4))) unsigned int u32x4;

// ws layout: Wswz[4*64*64*8 u16 = 256 KB] | logits[16384*64 f32 = 4 MB] | accum[512 f32] | counter[u32]
#define LOGITS_OFF 262144
#define ACCUM_OFF (262144 + 4194304)

// ===== INSTRUMENTATION BUILD: REPS=8 internal repeats so gate_gemm /
// gate_top outrank the harness's 78 us fillBuffer in rocprof top-5.
// True per-kernel dur = dispatch dur / 8. Semantics preserved.
#define REPS 8

// round-to-nearest-even fp32 -> bf16 (as u16)
#define RNE16(f) \
  ((unsigned short)((__float_as_uint(f) + 0x7fffu + ((__float_as_uint(f) >> 16) & 1u)) >> 16))

#define CVTPK(dst, a, b) \
  asm("v_cvt_pk_bf16_f32 %0, %1, %2" : "=v"(dst) : "v"(a), "v"(b))

// async global->LDS, 16 bytes per lane
#define GL16(gp, lp)                                                          \
  __builtin_amdgcn_global_load_lds(                                           \
      (const __attribute__((address_space(1))) unsigned int*)(gp),            \
      (__attribute__((address_space(3))) unsigned int*)(lp), 16, 0, 0)

// ---- kernel 0: W fp32 -> bf16, swizzled to MFMA-fragment-linear ----------
__global__ __launch_bounds__(256) void wconv(const float* __restrict__ W,
                                             unsigned short* __restrict__ Wswz,
                                             float* __restrict__ accum) {
  int t = blockIdx.x * 256 + threadIdx.x;  // 64 blocks -> 16384 threads
  int g = t >> 12, rem = t & 4095;
  int ks = rem >> 6, lane = rem & 63;
  int fm = lane & 15, kg = lane >> 4;
  const float* src = W + (size_t)(g * 16 + fm) * 2048 + ks * 32 + kg * 8;
  float4 a = *(const float4*)src;
  float4 b = *(const float4*)(src + 4);
  ushort4 lo = make_ushort4(RNE16(a.x), RNE16(a.y), RNE16(a.z), RNE16(a.w));
  ushort4 hi = make_ushort4(RNE16(b.x), RNE16(b.y), RNE16(b.z), RNE16(b.w));
  unsigned short* dst = Wswz + (size_t)t * 8;
  *(ushort4*)dst = lo;
  *(ushort4*)(dst + 4) = hi;
  if (blockIdx.x == 0) {
    accum[threadIdx.x] = 0.f;
    accum[256 + threadIdx.x] = 0.f;
    if (threadIdx.x == 0) ((unsigned*)accum)[512] = 0u;
  }
}

// ---- kernel 1: GEMM via global_load_lds double-buffered staging ----------
// Identical structure to R3; whole pipeline repeated REPS times (idempotent).
__global__ __launch_bounds__(256, 4) void gate_gemm(
    const float* __restrict__ x, const unsigned short* __restrict__ Wswz,
    float* __restrict__ logits) {
  __shared__ float __attribute__((aligned(16))) xlds[2][2048];

  const int tid = threadIdx.x;
  const int lane = tid & 63;
  const int w = __builtin_amdgcn_readfirstlane(tid >> 6);  // expert group 0..3
  const int fm = lane & 15;
  const int kg = lane >> 4;
  const int tok0 = blockIdx.x * 16;

  const float* src0;
  const float* src1;
  {
    int p0 = tid, q0 = p0 ^ ((p0 >> 5) & 7);
    int p1 = 256 + tid, q1 = p1 ^ ((p1 >> 5) & 7);
    src0 = x + (size_t)(tok0 + (q0 >> 5)) * 2048 + (q0 & 31) * 4;
    src1 = x + (size_t)(tok0 + (q1 >> 5)) * 2048 + (q1 & 31) * 4;
  }
  float* lds_d0 = &xlds[0][tid * 4];
  float* lds_d1 = &xlds[0][1024 + tid * 4];

  const char* lb0 = (const char*)xlds + fm * 512 + (((kg * 2 + 0) ^ (fm & 7)) * 16);
  const char* lb1 = (const char*)xlds + fm * 512 + (((kg * 2 + 1) ^ (fm & 7)) * 16);

  const bf16x8* wsw = (const bf16x8*)Wswz + lane;  // + (g*64 + absks)*64

#define STEP(BUF, S, DO_STAGE)                                               \
  {                                                                          \
    bf16x8 b0 = wsw[(w * 64 + (S) * 4 + 0) * 64];                            \
    bf16x8 b1 = wsw[(w * 64 + (S) * 4 + 1) * 64];                            \
    bf16x8 b2 = wsw[(w * 64 + (S) * 4 + 2) * 64];                            \
    bf16x8 b3 = wsw[(w * 64 + (S) * 4 + 3) * 64];                            \
    if (DO_STAGE) {                                                          \
      GL16(src0 + ((S) + 1) * 128, lds_d0 + (1 - (BUF)) * 2048);             \
      GL16(src1 + ((S) + 1) * 128, lds_d1 + (1 - (BUF)) * 2048);             \
    }                                                                        \
    _Pragma("unroll")                                                        \
    for (int ks = 0; ks < 4; ++ks) {                                         \
      float4 lo = *(const float4*)(lb0 + (BUF)*8192 + ks * 128);             \
      float4 hi = *(const float4*)(lb1 + (BUF)*8192 + ks * 128);             \
      unsigned u0, u1, u2, u3;                                               \
      CVTPK(u0, lo.x, lo.y);                                                 \
      CVTPK(u1, lo.z, lo.w);                                                 \
      CVTPK(u2, hi.x, hi.y);                                                 \
      CVTPK(u3, hi.z, hi.w);                                                 \
      u32x4 uu = (u32x4){u0, u1, u2, u3};                                    \
      bf16x8 a = __builtin_bit_cast(bf16x8, uu);                             \
      bf16x8 bb = (ks == 0) ? b0 : (ks == 1) ? b1 : (ks == 2) ? b2 : b3;     \
      acc = __builtin_amdgcn_mfma_f32_16x16x32_bf16(a, bb, acc, 0, 0, 0);    \
    }                                                                        \
    __syncthreads();                                                         \
  }

#pragma unroll 1
  for (int rep = 0; rep < REPS; ++rep) {
    f32x4 acc = (f32x4){0.f, 0.f, 0.f, 0.f};

    // prologue: stage step 0 into buf 0
    GL16(src0, lds_d0);
    GL16(src1, lds_d1);
    __syncthreads();

#pragma unroll 1
    for (int s = 0; s < 14; s += 2) {
      STEP(0, s, true)
      STEP(1, s + 1, true)
    }
    STEP(0, 14, true)
    STEP(1, 15, false)

    // C layout: token = kg*4 + r, expert = w*16 + fm  (stores kept every rep
    // so earlier reps are not DCE'd; values identical across reps)
#pragma unroll
    for (int r = 0; r < 4; ++r)
      logits[(size_t)(tok0 + kg * 4 + r) * 64 + w * 16 + fm] = acc[r];
  }
#undef STEP
}

// ---- kernel 2: wave-parallel epilogue ------------------------------------
// Identical structure to R3; token pipeline repeated REPS times; atomics and
// aux-loss finalize gated to the last rep (non-idempotent part).
__global__ __launch_bounds__(1024) void gate_top(
    const float* __restrict__ x, const float* __restrict__ Wf,
    const float* __restrict__ logits, float* __restrict__ out,
    float* __restrict__ accum) {
  __shared__ float sm[16][64];
  __shared__ float cn[16][64];

  const int tid = threadIdx.x;
  const int lane = tid & 63;
  const int w = tid >> 6;            // 0..15
  const int tok0 = blockIdx.x * 64;  // 64 tokens per block
  const int b = blockIdx.x >> 6;     // 64 blocks per batch row

#pragma unroll 1
  for (int rep = 0; rep < REPS; ++rep) {
    float ssum = 0.f;
    float cnt = 0.f;

    for (int i = 0; i < 4; ++i) {
      const int tok = tok0 + w * 4 + i;
      float v = logits[(size_t)tok * 64 + lane];

      // pass 1: m1/i1 (argmax, tie -> lower index)
      float m1 = v; int i1 = lane;
#pragma unroll
      for (int o = 32; o; o >>= 1) {
        float ov = __shfl_xor(m1, o, 64);
        int oi = __shfl_xor(i1, o, 64);
        if (ov > m1 || (ov == m1 && oi < i1)) { m1 = ov; i1 = oi; }
      }
      // pass 2: m2/i2
      float v2 = (lane == i1) ? -3e38f : v;
      float m2 = v2; int i2 = lane;
#pragma unroll
      for (int o = 32; o; o >>= 1) {
        float ov = __shfl_xor(m2, o, 64);
        int oi = __shfl_xor(i2, o, 64);
        if (ov > m2 || (ov == m2 && oi < i2)) { m2 = ov; i2 = oi; }
      }
      // pass 3: m3 (value only)
      float m3 = (lane == i1 || lane == i2) ? -3e38f : v;
#pragma unroll
      for (int o = 32; o; o >>= 1) m3 = fmaxf(m3, __shfl_xor(m3, o, 64));

      // near-tie: exact fp32 re-dot (wave-uniform branch)
      if ((m1 - m2 < TAU) || (m2 - m3 < TAU)) {
        unsigned long long cand = __ballot(v >= m2 - TAU);
        const float* xr2 = x + (size_t)tok * 2048 + lane * 32;
        while (cand) {
          int e = __ffsll(cand) - 1;
          cand &= cand - 1;
          const float* wr = Wf + (size_t)e * 2048 + lane * 32;
          float s = 0.f;
#pragma unroll
          for (int kk = 0; kk < 32; kk += 8) {
            float4 u0 = *(const float4*)(xr2 + kk);
            float4 w0 = *(const float4*)(wr + kk);
            float4 u1 = *(const float4*)(xr2 + kk + 4);
            float4 w1 = *(const float4*)(wr + kk + 4);
            s += u0.x * w0.x + u0.y * w0.y + u0.z * w0.z + u0.w * w0.w +
                 u1.x * w1.x + u1.y * w1.y + u1.z * w1.z + u1.w * w1.w;
          }
#pragma unroll
          for (int o = 32; o; o >>= 1) s += __shfl_xor(s, o, 64);
          if (lane == e) v = s;
        }
        // redo top-2 on corrected values
        m1 = v; i1 = lane;
#pragma unroll
        for (int o = 32; o; o >>= 1) {
          float ov = __shfl_xor(m1, o, 64);
          int oi = __shfl_xor(i1, o, 64);
          if (ov > m1 || (ov == m1 && oi < i1)) { m1 = ov; i1 = oi; }
        }
        v2 = (lane == i1) ? -3e38f : v;
        m2 = v2; i2 = lane;
#pragma unroll
        for (int o = 32; o; o >>= 1) {
          float ov = __shfl_xor(m2, o, 64);
          int oi = __shfl_xor(i2, o, 64);
          if (ov > m2 || (ov == m2 && oi < i2)) { m2 = ov; i2 = oi; }
        }
      }

      // softmax pieces
      float ez = __expf(v - m1);
      float Z = ez;
#pragma unroll
      for (int o = 32; o; o >>= 1) Z += __shfl_xor(Z, o, 64);
      float iz = 1.f / Z;
      float p1 = iz;
      float p2 = __expf(m2 - m1) * iz;
      float dn = 1.f / (p1 + p2 + 1e-20f);
      if (lane == 0) {
        size_t tg = (size_t)tok;
        out[tg * 2 + 0] = (float)i1;
        out[tg * 2 + 1] = (float)i2;
        out[32768 + tg * 2 + 0] = p1 * dn;
        out[32768 + tg * 2 + 1] = p2 * dn;
      }
      ssum += ez * iz;
      cnt += (float)((lane == i1) + (lane == i2));
    }

    // keep reps 0..REPS-2 alive without committing them (rule #17)
    asm volatile("" ::"v"(ssum), "v"(cnt));

    if (rep == REPS - 1) {
      sm[w][lane] = ssum;
      cn[w][lane] = cnt;
      __syncthreads();

      if (tid < 64) {  // wave 0: cross-wave reduce + one atomic per expert
        float s = 0.f, c = 0.f;
#pragma unroll
        for (int ww = 0; ww < 16; ++ww) { s += sm[ww][tid]; c += cn[ww][tid]; }
        atomicAdd(&accum[b * 64 + tid], s);
        atomicAdd(&accum[256 + b * 64 + tid], c);

        // last block finalizes aux loss
        __threadfence();
        unsigned old = 0;
        if (tid == 0) old = atomicAdd((unsigned*)accum + 512, 1u);
        old = (unsigned)__shfl((int)old, 0, 64);
        if (old == 255u) {
          __threadfence();
          float tot = 0.f;
#pragma unroll
          for (int bb = 0; bb < 4; ++bb) {
            float ss = atomicAdd(&accum[bb * 64 + tid], 0.f);
            float cc = atomicAdd(&accum[256 + bb * 64 + tid], 0.f);
            tot += cc * (1.f / 128.f) * (ss * (1.f / 4096.f));
          }
#pragma unroll
          for (int o = 32; o; o >>= 1) tot += __shfl_xor(tot, o, 64);
          if (tid == 0) out[65536] = 0.025f * tot;  // alpha/B = 0.1/4
        }
      }
    }
  }
}

extern "C" void kernel_launch(void* const* d_in, const int* in_sizes, int n_in,
                              void* d_out, int out_size, void* d_ws, size_t ws_size,
                              hipStream_t stream) {
  const float* x = (const float*)d_in[0];
  const float* Wf = (const float*)d_in[1];
  float* out = (float*)d_out;
  unsigned short* Wswz = (unsigned short*)d_ws;
  float* logits = (float*)((char*)d_ws + LOGITS_OFF);
  float* accum = (float*)((char*)d_ws + ACCUM_OFF);
  wconv<<<64, 256, 0, stream>>>(Wf, Wswz, accum);
  gate_gemm<<<1024, 256, 0, stream>>>(x, Wswz, logits);
  gate_top<<<256, 1024, 0, stream>>>(x, Wf, logits, out, accum);
}

// Round 5
// 244.578 us; speedup vs baseline: 1.9265x; 1.9265x over previous
//
#include <hip/hip_runtime.h>

#define TAU 8e-3f

typedef __attribute__((ext_vector_type(8))) short bf16x8;
typedef __attribute__((ext_vector_type(4))) float f32x4;
typedef __attribute__((ext_vector_type(4))) unsigned int u32x4;

// ws layout: Wswz[4*64*64*8 u16 = 256 KB] | (4 MB unused) | accum[512 f32] | counter[u32]
#define ACCUM_OFF (262144 + 4194304)

// round-to-nearest-even fp32 -> bf16 (as u16)
#define RNE16(f) \
  ((unsigned short)((__float_as_uint(f) + 0x7fffu + ((__float_as_uint(f) >> 16) & 1u)) >> 16))

#define CVTPK(dst, a, b) \
  asm("v_cvt_pk_bf16_f32 %0, %1, %2" : "=v"(dst) : "v"(a), "v"(b))

// async global->LDS, 16 bytes per lane
#define GL16(gp, lp)                                                          \
  __builtin_amdgcn_global_load_lds(                                           \
      (const __attribute__((address_space(1))) unsigned int*)(gp),            \
      (__attribute__((address_space(3))) unsigned int*)(lp), 16, 0, 0)

// ---- kernel 0: W fp32 -> bf16, swizzled to MFMA-fragment-linear ----------
// Wswz[g][ks][lane] (8 u16 each): lane(fm,kg) holds W[g*16+fm][ks*32+kg*8 .. +8]
__global__ __launch_bounds__(256) void wconv(const float* __restrict__ W,
                                             unsigned short* __restrict__ Wswz,
                                             float* __restrict__ accum) {
  int t = blockIdx.x * 256 + threadIdx.x;  // 64 blocks -> 16384 threads
  int g = t >> 12, rem = t & 4095;
  int ks = rem >> 6, lane = rem & 63;
  int fm = lane & 15, kg = lane >> 4;
  const float* src = W + (size_t)(g * 16 + fm) * 2048 + ks * 32 + kg * 8;
  float4 a = *(const float4*)src;
  float4 b = *(const float4*)(src + 4);
  ushort4 lo = make_ushort4(RNE16(a.x), RNE16(a.y), RNE16(a.z), RNE16(a.w));
  ushort4 hi = make_ushort4(RNE16(b.x), RNE16(b.y), RNE16(b.z), RNE16(b.w));
  unsigned short* dst = Wswz + (size_t)t * 8;
  *(ushort4*)dst = lo;
  *(ushort4*)(dst + 4) = hi;
  if (blockIdx.x == 0) {
    accum[threadIdx.x] = 0.f;
    accum[256 + threadIdx.x] = 0.f;
    if (threadIdx.x == 0) ((unsigned*)accum)[512] = 0u;
  }
}

// ---- kernel 1: fused GEMM + epilogue -------------------------------------
// 1024 blocks x 256 threads (4 waves). Block: 16 tokens. Wave w: experts
// [w*16, w*16+16), FULL K=2048 -> one f32x4 accumulator.
// K-loop: identical to R3 (global_load_lds double-buffered, swizzled).
// Epilogue: block's 16x64 scores -> part LDS; wave w handles tokens
// w*4..w*4+3, lane=expert (gate_top's verified wave-parallel code).
__global__ __launch_bounds__(256, 4) void gate_fused(
    const float* __restrict__ x, const float* __restrict__ Wf,
    const unsigned short* __restrict__ Wswz,
    float* __restrict__ out, float* __restrict__ accum) {
  __shared__ float __attribute__((aligned(16))) xlds[2][2048];
  __shared__ float part[16][68];  // [token][expert], pitch 68: 2-way banks
  __shared__ float sm[4][64];
  __shared__ float cn[4][64];

  const int tid = threadIdx.x;
  const int lane = tid & 63;
  const int w = __builtin_amdgcn_readfirstlane(tid >> 6);  // expert group 0..3
  const int fm = lane & 15;
  const int kg = lane >> 4;
  const int tok0 = blockIdx.x * 16;

  const float* src0;
  const float* src1;
  {
    int p0 = tid, q0 = p0 ^ ((p0 >> 5) & 7);
    int p1 = 256 + tid, q1 = p1 ^ ((p1 >> 5) & 7);
    src0 = x + (size_t)(tok0 + (q0 >> 5)) * 2048 + (q0 & 31) * 4;
    src1 = x + (size_t)(tok0 + (q1 >> 5)) * 2048 + (q1 & 31) * 4;
  }
  float* lds_d0 = &xlds[0][tid * 4];
  float* lds_d1 = &xlds[0][1024 + tid * 4];

  const char* lb0 = (const char*)xlds + fm * 512 + (((kg * 2 + 0) ^ (fm & 7)) * 16);
  const char* lb1 = (const char*)xlds + fm * 512 + (((kg * 2 + 1) ^ (fm & 7)) * 16);

  const bf16x8* wsw = (const bf16x8*)Wswz + lane;  // + (g*64 + absks)*64

  f32x4 acc = (f32x4){0.f, 0.f, 0.f, 0.f};

#define STEP(BUF, S, DO_STAGE)                                               \
  {                                                                          \
    bf16x8 b0 = wsw[(w * 64 + (S) * 4 + 0) * 64];                            \
    bf16x8 b1 = wsw[(w * 64 + (S) * 4 + 1) * 64];                            \
    bf16x8 b2 = wsw[(w * 64 + (S) * 4 + 2) * 64];                            \
    bf16x8 b3 = wsw[(w * 64 + (S) * 4 + 3) * 64];                            \
    if (DO_STAGE) {                                                          \
      GL16(src0 + ((S) + 1) * 128, lds_d0 + (1 - (BUF)) * 2048);             \
      GL16(src1 + ((S) + 1) * 128, lds_d1 + (1 - (BUF)) * 2048);             \
    }                                                                        \
    _Pragma("unroll")                                                        \
    for (int ks = 0; ks < 4; ++ks) {                                         \
      float4 lo = *(const float4*)(lb0 + (BUF)*8192 + ks * 128);             \
      float4 hi = *(const float4*)(lb1 + (BUF)*8192 + ks * 128);             \
      unsigned u0, u1, u2, u3;                                               \
      CVTPK(u0, lo.x, lo.y);                                                 \
      CVTPK(u1, lo.z, lo.w);                                                 \
      CVTPK(u2, hi.x, hi.y);                                                 \
      CVTPK(u3, hi.z, hi.w);                                                 \
      u32x4 uu = (u32x4){u0, u1, u2, u3};                                    \
      bf16x8 a = __builtin_bit_cast(bf16x8, uu);                             \
      bf16x8 bb = (ks == 0) ? b0 : (ks == 1) ? b1 : (ks == 2) ? b2 : b3;     \
      acc = __builtin_amdgcn_mfma_f32_16x16x32_bf16(a, bb, acc, 0, 0, 0);    \
    }                                                                        \
    __syncthreads();                                                         \
  }

  // prologue: stage step 0 into buf 0
  GL16(src0, lds_d0);
  GL16(src1, lds_d1);
  __syncthreads();

#pragma unroll 1
  for (int s = 0; s < 14; s += 2) {
    STEP(0, s, true)
    STEP(1, s + 1, true)
  }
  STEP(0, 14, true)
  STEP(1, 15, false)
#undef STEP

  // scores -> LDS. token = kg*4 + r, expert = w*16 + fm
#pragma unroll
  for (int r = 0; r < 4; ++r) part[kg * 4 + r][w * 16 + fm] = acc[r];
  __syncthreads();

  // ---- epilogue: wave w handles tokens w*4 .. w*4+3, lane = expert -------
  float ssum = 0.f;
  float cnt = 0.f;

  for (int i = 0; i < 4; ++i) {
    const int tl = w * 4 + i;
    const int tok = tok0 + tl;
    float v = part[tl][lane];

    // pass 1: m1/i1 (argmax, tie -> lower index)
    float m1 = v; int i1 = lane;
#pragma unroll
    for (int o = 32; o; o >>= 1) {
      float ov = __shfl_xor(m1, o, 64);
      int oi = __shfl_xor(i1, o, 64);
      if (ov > m1 || (ov == m1 && oi < i1)) { m1 = ov; i1 = oi; }
    }
    // pass 2: m2/i2
    float v2 = (lane == i1) ? -3e38f : v;
    float m2 = v2; int i2 = lane;
#pragma unroll
    for (int o = 32; o; o >>= 1) {
      float ov = __shfl_xor(m2, o, 64);
      int oi = __shfl_xor(i2, o, 64);
      if (ov > m2 || (ov == m2 && oi < i2)) { m2 = ov; i2 = oi; }
    }
    // pass 3: m3 (value only)
    float m3 = (lane == i1 || lane == i2) ? -3e38f : v;
#pragma unroll
    for (int o = 32; o; o >>= 1) m3 = fmaxf(m3, __shfl_xor(m3, o, 64));

    // near-tie: exact fp32 re-dot (wave-uniform branch)
    if ((m1 - m2 < TAU) || (m2 - m3 < TAU)) {
      unsigned long long cand = __ballot(v >= m2 - TAU);
      const float* xr2 = x + (size_t)tok * 2048 + lane * 32;
      while (cand) {
        int e = __ffsll(cand) - 1;
        cand &= cand - 1;
        const float* wr = Wf + (size_t)e * 2048 + lane * 32;
        float s = 0.f;
#pragma unroll
        for (int kk = 0; kk < 32; kk += 8) {
          float4 u0 = *(const float4*)(xr2 + kk);
          float4 w0 = *(const float4*)(wr + kk);
          float4 u1 = *(const float4*)(xr2 + kk + 4);
          float4 w1 = *(const float4*)(wr + kk + 4);
          s += u0.x * w0.x + u0.y * w0.y + u0.z * w0.z + u0.w * w0.w +
               u1.x * w1.x + u1.y * w1.y + u1.z * w1.z + u1.w * w1.w;
        }
#pragma unroll
        for (int o = 32; o; o >>= 1) s += __shfl_xor(s, o, 64);
        if (lane == e) v = s;  // butterfly gave all lanes the sum
      }
      // redo top-2 on corrected values
      m1 = v; i1 = lane;
#pragma unroll
      for (int o = 32; o; o >>= 1) {
        float ov = __shfl_xor(m1, o, 64);
        int oi = __shfl_xor(i1, o, 64);
        if (ov > m1 || (ov == m1 && oi < i1)) { m1 = ov; i1 = oi; }
      }
      v2 = (lane == i1) ? -3e38f : v;
      m2 = v2; i2 = lane;
#pragma unroll
      for (int o = 32; o; o >>= 1) {
        float ov = __shfl_xor(m2, o, 64);
        int oi = __shfl_xor(i2, o, 64);
        if (ov > m2 || (ov == m2 && oi < i2)) { m2 = ov; i2 = oi; }
      }
    }

    // softmax pieces
    float ez = __expf(v - m1);
    float Z = ez;
#pragma unroll
    for (int o = 32; o; o >>= 1) Z += __shfl_xor(Z, o, 64);
    float iz = 1.f / Z;
    float p1 = iz;                   // exp(m1-m1)*iz
    float p2 = __expf(m2 - m1) * iz;
    float dn = 1.f / (p1 + p2 + 1e-20f);
    if (lane == 0) {
      size_t tg = (size_t)tok;
      out[tg * 2 + 0] = (float)i1;
      out[tg * 2 + 1] = (float)i2;
      out[32768 + tg * 2 + 0] = p1 * dn;
      out[32768 + tg * 2 + 1] = p2 * dn;
    }
    ssum += ez * iz;                      // per-(b, expert=lane) softmax sum
    cnt += (float)((lane == i1) + (lane == i2));
  }

  sm[w][lane] = ssum;
  cn[w][lane] = cnt;
  __syncthreads();

  if (tid < 64) {  // wave 0: cross-wave reduce + one atomic per expert
    const int b = blockIdx.x >> 8;  // 256 blocks per batch row
    float s = 0.f, c = 0.f;
#pragma unroll
    for (int ww = 0; ww < 4; ++ww) { s += sm[ww][tid]; c += cn[ww][tid]; }
    atomicAdd(&accum[b * 64 + tid], s);
    atomicAdd(&accum[256 + b * 64 + tid], c);

    // last block finalizes aux loss
    __threadfence();
    unsigned old = 0;
    if (tid == 0) old = atomicAdd((unsigned*)accum + 512, 1u);
    old = (unsigned)__shfl((int)old, 0, 64);
    if (old == 1023u) {
      __threadfence();
      float tot = 0.f;
#pragma unroll
      for (int bb = 0; bb < 4; ++bb) {
        float ss = atomicAdd(&accum[bb * 64 + tid], 0.f);
        float cc = atomicAdd(&accum[256 + bb * 64 + tid], 0.f);
        tot += cc * (1.f / 128.f) * (ss * (1.f / 4096.f));
      }
#pragma unroll
      for (int o = 32; o; o >>= 1) tot += __shfl_xor(tot, o, 64);
      if (tid == 0) out[65536] = 0.025f * tot;  // alpha/B = 0.1/4
    }
  }
}

extern "C" void kernel_launch(void* const* d_in, const int* in_sizes, int n_in,
                              void* d_out, int out_size, void* d_ws, size_t ws_size,
                              hipStream_t stream) {
  const float* x = (const float*)d_in[0];
  const float* Wf = (const float*)d_in[1];
  float* out = (float*)d_out;
  unsigned short* Wswz = (unsigned short*)d_ws;
  float* accum = (float*)((char*)d_ws + ACCUM_OFF);
  wconv<<<64, 256, 0, stream>>>(Wf, Wswz, accum);
  gate_fused<<<1024, 256, 0, stream>>>(x, Wf, Wswz, out, accum);
}

// Round 6
// 214.567 us; speedup vs baseline: 2.1959x; 1.1399x over previous
//
#include <hip/hip_runtime.h>

#define TAU 8e-3f

typedef __attribute__((ext_vector_type(8))) short bf16x8;
typedef __attribute__((ext_vector_type(4))) float f32x4;
typedef __attribute__((ext_vector_type(4))) unsigned int u32x4;

// ws layout: Wswz[4*64*64*8 u16 = 256 KB] | ps[1024*64 f32 = 256 KB] | pc[1024*64 f32 = 256 KB]
#define PS_OFF 262144
#define PC_OFF (262144 + 262144)

// round-to-nearest-even fp32 -> bf16 (as u16)
#define RNE16(f) \
  ((unsigned short)((__float_as_uint(f) + 0x7fffu + ((__float_as_uint(f) >> 16) & 1u)) >> 16))

#define CVTPK(dst, a, b) \
  asm("v_cvt_pk_bf16_f32 %0, %1, %2" : "=v"(dst) : "v"(a), "v"(b))

// async global->LDS, 16 bytes per lane
#define GL16(gp, lp)                                                          \
  __builtin_amdgcn_global_load_lds(                                           \
      (const __attribute__((address_space(1))) unsigned int*)(gp),            \
      (__attribute__((address_space(3))) unsigned int*)(lp), 16, 0, 0)

// ---- kernel 0: W fp32 -> bf16, swizzled to MFMA-fragment-linear ----------
// Wswz[g][ks][lane] (8 u16 each): lane(fm,kg) holds W[g*16+fm][ks*32+kg*8 .. +8]
__global__ __launch_bounds__(256) void wconv(const float* __restrict__ W,
                                             unsigned short* __restrict__ Wswz) {
  int t = blockIdx.x * 256 + threadIdx.x;  // 64 blocks -> 16384 threads
  int g = t >> 12, rem = t & 4095;
  int ks = rem >> 6, lane = rem & 63;
  int fm = lane & 15, kg = lane >> 4;
  const float* src = W + (size_t)(g * 16 + fm) * 2048 + ks * 32 + kg * 8;
  float4 a = *(const float4*)src;
  float4 b = *(const float4*)(src + 4);
  ushort4 lo = make_ushort4(RNE16(a.x), RNE16(a.y), RNE16(a.z), RNE16(a.w));
  ushort4 hi = make_ushort4(RNE16(b.x), RNE16(b.y), RNE16(b.z), RNE16(b.w));
  unsigned short* dst = Wswz + (size_t)t * 8;
  *(ushort4*)dst = lo;
  *(ushort4*)(dst + 4) = hi;
}

// ---- kernel 1: fused GEMM + epilogue (NO atomics, NO fences) --------------
// 1024 blocks x 256 threads (4 waves). Block: 16 tokens. Wave w: experts
// [w*16, w*16+16), FULL K=2048 -> one f32x4 accumulator.
// K-loop: identical to R3/R5 (global_load_lds double-buffered, swizzled).
// Aux-loss partials written to per-block slots; reduced by aux_final.
__global__ __launch_bounds__(256, 4) void gate_fused(
    const float* __restrict__ x, const float* __restrict__ Wf,
    const unsigned short* __restrict__ Wswz,
    float* __restrict__ out, float* __restrict__ ps, float* __restrict__ pc) {
  __shared__ float __attribute__((aligned(16))) xlds[2][2048];
  __shared__ float part[16][68];  // [token][expert], pitch 68: 2-way banks
  __shared__ float sm[4][64];
  __shared__ float cn[4][64];

  const int tid = threadIdx.x;
  const int lane = tid & 63;
  const int w = __builtin_amdgcn_readfirstlane(tid >> 6);  // expert group 0..3
  const int fm = lane & 15;
  const int kg = lane >> 4;
  const int tok0 = blockIdx.x * 16;

  const float* src0;
  const float* src1;
  {
    int p0 = tid, q0 = p0 ^ ((p0 >> 5) & 7);
    int p1 = 256 + tid, q1 = p1 ^ ((p1 >> 5) & 7);
    src0 = x + (size_t)(tok0 + (q0 >> 5)) * 2048 + (q0 & 31) * 4;
    src1 = x + (size_t)(tok0 + (q1 >> 5)) * 2048 + (q1 & 31) * 4;
  }
  float* lds_d0 = &xlds[0][tid * 4];
  float* lds_d1 = &xlds[0][1024 + tid * 4];

  const char* lb0 = (const char*)xlds + fm * 512 + (((kg * 2 + 0) ^ (fm & 7)) * 16);
  const char* lb1 = (const char*)xlds + fm * 512 + (((kg * 2 + 1) ^ (fm & 7)) * 16);

  const bf16x8* wsw = (const bf16x8*)Wswz + lane;  // + (g*64 + absks)*64

  f32x4 acc = (f32x4){0.f, 0.f, 0.f, 0.f};

#define STEP(BUF, S, DO_STAGE)                                               \
  {                                                                          \
    bf16x8 b0 = wsw[(w * 64 + (S) * 4 + 0) * 64];                            \
    bf16x8 b1 = wsw[(w * 64 + (S) * 4 + 1) * 64];                            \
    bf16x8 b2 = wsw[(w * 64 + (S) * 4 + 2) * 64];                            \
    bf16x8 b3 = wsw[(w * 64 + (S) * 4 + 3) * 64];                            \
    if (DO_STAGE) {                                                          \
      GL16(src0 + ((S) + 1) * 128, lds_d0 + (1 - (BUF)) * 2048);             \
      GL16(src1 + ((S) + 1) * 128, lds_d1 + (1 - (BUF)) * 2048);             \
    }                                                                        \
    _Pragma("unroll")                                                        \
    for (int ks = 0; ks < 4; ++ks) {                                         \
      float4 lo = *(const float4*)(lb0 + (BUF)*8192 + ks * 128);             \
      float4 hi = *(const float4*)(lb1 + (BUF)*8192 + ks * 128);             \
      unsigned u0, u1, u2, u3;                                               \
      CVTPK(u0, lo.x, lo.y);                                                 \
      CVTPK(u1, lo.z, lo.w);                                                 \
      CVTPK(u2, hi.x, hi.y);                                                 \
      CVTPK(u3, hi.z, hi.w);                                                 \
      u32x4 uu = (u32x4){u0, u1, u2, u3};                                    \
      bf16x8 a = __builtin_bit_cast(bf16x8, uu);                             \
      bf16x8 bb = (ks == 0) ? b0 : (ks == 1) ? b1 : (ks == 2) ? b2 : b3;     \
      acc = __builtin_amdgcn_mfma_f32_16x16x32_bf16(a, bb, acc, 0, 0, 0);    \
    }                                                                        \
    __syncthreads();                                                         \
  }

  // prologue: stage step 0 into buf 0
  GL16(src0, lds_d0);
  GL16(src1, lds_d1);
  __syncthreads();

#pragma unroll 1
  for (int s = 0; s < 14; s += 2) {
    STEP(0, s, true)
    STEP(1, s + 1, true)
  }
  STEP(0, 14, true)
  STEP(1, 15, false)
#undef STEP

  // scores -> LDS. token = kg*4 + r, expert = w*16 + fm
#pragma unroll
  for (int r = 0; r < 4; ++r) part[kg * 4 + r][w * 16 + fm] = acc[r];
  __syncthreads();

  // ---- epilogue: wave w handles tokens w*4 .. w*4+3, lane = expert -------
  float ssum = 0.f;
  float cnt = 0.f;

  for (int i = 0; i < 4; ++i) {
    const int tl = w * 4 + i;
    const int tok = tok0 + tl;
    float v = part[tl][lane];

    // pass 1: m1/i1 (argmax, tie -> lower index)
    float m1 = v; int i1 = lane;
#pragma unroll
    for (int o = 32; o; o >>= 1) {
      float ov = __shfl_xor(m1, o, 64);
      int oi = __shfl_xor(i1, o, 64);
      if (ov > m1 || (ov == m1 && oi < i1)) { m1 = ov; i1 = oi; }
    }
    // pass 2: m2/i2
    float v2 = (lane == i1) ? -3e38f : v;
    float m2 = v2; int i2 = lane;
#pragma unroll
    for (int o = 32; o; o >>= 1) {
      float ov = __shfl_xor(m2, o, 64);
      int oi = __shfl_xor(i2, o, 64);
      if (ov > m2 || (ov == m2 && oi < i2)) { m2 = ov; i2 = oi; }
    }
    // pass 3: m3 (value only)
    float m3 = (lane == i1 || lane == i2) ? -3e38f : v;
#pragma unroll
    for (int o = 32; o; o >>= 1) m3 = fmaxf(m3, __shfl_xor(m3, o, 64));

    // near-tie: exact fp32 re-dot (wave-uniform branch)
    if ((m1 - m2 < TAU) || (m2 - m3 < TAU)) {
      unsigned long long cand = __ballot(v >= m2 - TAU);
      const float* xr2 = x + (size_t)tok * 2048 + lane * 32;
      while (cand) {
        int e = __ffsll(cand) - 1;
        cand &= cand - 1;
        const float* wr = Wf + (size_t)e * 2048 + lane * 32;
        float s = 0.f;
#pragma unroll
        for (int kk = 0; kk < 32; kk += 8) {
          float4 u0 = *(const float4*)(xr2 + kk);
          float4 w0 = *(const float4*)(wr + kk);
          float4 u1 = *(const float4*)(xr2 + kk + 4);
          float4 w1 = *(const float4*)(wr + kk + 4);
          s += u0.x * w0.x + u0.y * w0.y + u0.z * w0.z + u0.w * w0.w +
               u1.x * w1.x + u1.y * w1.y + u1.z * w1.z + u1.w * w1.w;
        }
#pragma unroll
        for (int o = 32; o; o >>= 1) s += __shfl_xor(s, o, 64);
        if (lane == e) v = s;  // butterfly gave all lanes the sum
      }
      // redo top-2 on corrected values
      m1 = v; i1 = lane;
#pragma unroll
      for (int o = 32; o; o >>= 1) {
        float ov = __shfl_xor(m1, o, 64);
        int oi = __shfl_xor(i1, o, 64);
        if (ov > m1 || (ov == m1 && oi < i1)) { m1 = ov; i1 = oi; }
      }
      v2 = (lane == i1) ? -3e38f : v;
      m2 = v2; i2 = lane;
#pragma unroll
      for (int o = 32; o; o >>= 1) {
        float ov = __shfl_xor(m2, o, 64);
        int oi = __shfl_xor(i2, o, 64);
        if (ov > m2 || (ov == m2 && oi < i2)) { m2 = ov; i2 = oi; }
      }
    }

    // softmax pieces
    float ez = __expf(v - m1);
    float Z = ez;
#pragma unroll
    for (int o = 32; o; o >>= 1) Z += __shfl_xor(Z, o, 64);
    float iz = 1.f / Z;
    float p1 = iz;                   // exp(m1-m1)*iz
    float p2 = __expf(m2 - m1) * iz;
    float dn = 1.f / (p1 + p2 + 1e-20f);
    if (lane == 0) {
      size_t tg = (size_t)tok;
      out[tg * 2 + 0] = (float)i1;
      out[tg * 2 + 1] = (float)i2;
      out[32768 + tg * 2 + 0] = p1 * dn;
      out[32768 + tg * 2 + 1] = p2 * dn;
    }
    ssum += ez * iz;                      // per-(b, expert=lane) softmax sum
    cnt += (float)((lane == i1) + (lane == i2));
  }

  sm[w][lane] = ssum;
  cn[w][lane] = cnt;
  __syncthreads();

  if (tid < 64) {  // wave 0: cross-wave reduce; plain coalesced partial store
    float s = 0.f, c = 0.f;
#pragma unroll
    for (int ww = 0; ww < 4; ++ww) { s += sm[ww][tid]; c += cn[ww][tid]; }
    ps[(size_t)blockIdx.x * 64 + tid] = s;
    pc[(size_t)blockIdx.x * 64 + tid] = c;
  }
}

// ---- kernel 2: deterministic aux-loss reduction ---------------------------
// 1 block x 1024 threads (16 waves). Thread (q, b, e): q=tid>>8, b=(tid>>6)&3,
// e=tid&63; sums 64 block-rows of batch b, chunk q. Coalesced 256 B/wave reads.
__global__ __launch_bounds__(1024) void aux_final(
    const float* __restrict__ ps, const float* __restrict__ pc,
    float* __restrict__ out) {
  __shared__ float rs[1024], rc[1024];
  const int tid = threadIdx.x;
  const int e = tid & 63;
  const int b = (tid >> 6) & 3;
  const int q = tid >> 8;

  float s = 0.f, c = 0.f;
#pragma unroll 8
  for (int i = 0; i < 64; ++i) {
    int blk = b * 256 + q * 64 + i;
    s += ps[(size_t)blk * 64 + e];
    c += pc[(size_t)blk * 64 + e];
  }
  rs[tid] = s;
  rc[tid] = c;
  __syncthreads();

  if (tid < 256) {  // combine 4 chunks, then (cnt/128)*(ssum/4096)
    float ss = rs[tid] + rs[256 + tid] + rs[512 + tid] + rs[768 + tid];
    float cc = rc[tid] + rc[256 + tid] + rc[512 + tid] + rc[768 + tid];
    rs[tid] = cc * (1.f / 128.f) * (ss * (1.f / 4096.f));
  }
  __syncthreads();
  if (tid < 64) {
    float tot = rs[tid] + rs[64 + tid] + rs[128 + tid] + rs[192 + tid];
#pragma unroll
    for (int o = 32; o; o >>= 1) tot += __shfl_xor(tot, o, 64);
    if (tid == 0) out[65536] = 0.025f * tot;  // alpha/B = 0.1/4
  }
}

extern "C" void kernel_launch(void* const* d_in, const int* in_sizes, int n_in,
                              void* d_out, int out_size, void* d_ws, size_t ws_size,
                              hipStream_t stream) {
  const float* x = (const float*)d_in[0];
  const float* Wf = (const float*)d_in[1];
  float* out = (float*)d_out;
  unsigned short* Wswz = (unsigned short*)d_ws;
  float* ps = (float*)((char*)d_ws + PS_OFF);
  float* pc = (float*)((char*)d_ws + PC_OFF);
  wconv<<<64, 256, 0, stream>>>(Wf, Wswz);
  gate_fused<<<1024, 256, 0, stream>>>(x, Wf, Wswz, out, ps, pc);
  aux_final<<<1, 1024, 0, stream>>>(ps, pc, out);
}